// Round 2
// baseline (253.144 us; speedup 1.0000x reference)
//
#include <hip/hip_runtime.h>

// ---------------------------------------------------------------------------
// CrossAttention: B=8, T=S=1024, E=H=768, fp32 in/out, bf16 MFMA internally.
//
// Round 11: 256x128 tile, BK=64, 512 threads (8 waves, 4m x 2n), 96 KiB LDS
// double-buffered, quadrant-phased schedule (T3/T4/T5-style):
//   per K-tile: B1 -> stage p0(t+1) -> vmcnt(2) -> B2 -> stage p1..p3(t+1)
//               -> 4 x { 8 ds_read_b128 ; setprio(1) ; 8 MFMA ; setprio(0) }
// vmcnt never drains in the main loop (2 loads in flight at each wait; 6
// issued a full tile-window before their deadline). Staging targets only the
// buffer whose reads finished before B1 -> tile-granular WAR safety; B2 after
// every wave's vmcnt(2) publishes landing cross-wave.
// Rationale: R10 doubled occupancy (15.5->28%) with zero speedup => 2-phase
// critical path is stage+barrier, occupancy-insensitive (m233). Regime-gate
// says tile size + phase-split is the lever. 256x128 also packs all grids
// into <=1.1 scheduler rounds (576/256/192/192 blocks at 1 block/CU).
// Swizzle: same 64B-row XOR-slot pattern as r9 (measured 0 conflicts).
// ---------------------------------------------------------------------------

typedef __bf16 bf16x8 __attribute__((ext_vector_type(8)));
typedef float  f32x4  __attribute__((ext_vector_type(4)));

#define WAIT_VM2 __builtin_amdgcn_s_waitcnt(0x0F72)   // vmcnt(2), lgkm/exp nowait
#define WAIT_VM0 __builtin_amdgcn_s_waitcnt(0x0F70)   // vmcnt(0)
#define BAR      __builtin_amdgcn_s_barrier()

__device__ __forceinline__ unsigned short f2bf(float f) {
    unsigned int u = __float_as_uint(f);
    u += 0x7fffu + ((u >> 16) & 1u);   // RNE; inputs are finite
    return (unsigned short)(u >> 16);
}

__device__ __forceinline__ void async_copy16(const void* g, void* s) {
    __builtin_amdgcn_global_load_lds(
        (const __attribute__((address_space(1))) void*)g,
        (__attribute__((address_space(3))) void*)s, 16, 0, 0);
}

// Block computes C[row0:row0+256, col0:col0+128].
// Ag = A + row0*K ([*,K] bf16 row-major); Bg = B^T + col0*K ([*,K]).
// Exactly one of Cf/Cb non-null. transC: store C^T as [b][H][S] (vt).
__device__ __forceinline__ void gemm_core(
    const unsigned short* __restrict__ Ag,
    const unsigned short* __restrict__ Bg,
    const int K,
    float* __restrict__ Cf, unsigned short* __restrict__ Cb,
    const long ldc, const int transC, const float* __restrict__ bias,
    const float scale, const long row0, const long col0)
{
    __shared__ __align__(16) unsigned short As0[16384];  // [256][64] swizzled
    __shared__ __align__(16) unsigned short As1[16384];
    __shared__ __align__(16) unsigned short Bs0[8192];   // [128][64] swizzled
    __shared__ __align__(16) unsigned short Bs1[8192];

    const int tid  = threadIdx.x;        // 0..511
    const int lane = tid & 63;
    const int quad = lane >> 4;
    const int l16  = lane & 15;
    const int wv   = tid >> 6;           // 0..7
    const int wm   = (wv >> 1) * 64;     // wave A-row base: 0..192
    const int wn   = (wv & 1) * 64;      // wave B-row base: 0 or 64

    // DMA staging: inst h, thread tid covers 16B chunk c = h*512 + tid.
    // Dest row r = c>>3 = h*64 + (tid>>3), linear slot s = tid&7.
    // Stored k-chunk at (r,s) is s ^ (r&7) = (tid&7) ^ ((tid>>3)&7)  (h*64==0 mod 8).
    const int ksw = ((tid & 7) ^ ((tid >> 3) & 7)) * 8;     // src k-offset, elems
    const unsigned short* a_src = Ag + (long)(tid >> 3) * K + ksw;
    const unsigned short* b_src = Bg + (long)(tid >> 3) * K + ksw;
    const int dofs = tid * 8;            // LDS dst elems; inst h adds h*4096

    f32x4 acc[4][4];
#pragma unroll
    for (int i = 0; i < 4; ++i)
#pragma unroll
        for (int j = 0; j < 4; ++j)
            acc[i][j] = f32x4{0.f, 0.f, 0.f, 0.f};

    auto stA = [&](unsigned short* dA, int h, int kk) {
        async_copy16(a_src + (long)(h * 64) * K + kk, &dA[h * 4096 + dofs]);
    };
    auto stB = [&](unsigned short* dB, int h, int kk) {
        async_copy16(b_src + (long)(h * 64) * K + kk, &dB[h * 4096 + dofs]);
    };

    // one quadrant: 2m x 2n frags x 2 k-slabs = 8 MFMA, 8 ds_read_b128
    auto do_quad = [&](const unsigned short* sA, const unsigned short* sB,
                       int mh, int nh) {
        bf16x8 af[2][2], bfr[2][2];
#pragma unroll
        for (int ks = 0; ks < 2; ++ks) {
            const int sl = ((quad + ks * 4) ^ (l16 & 7)) * 8;   // phys slot, elems
#pragma unroll
            for (int i = 0; i < 2; ++i) {
                af[i][ks]  = *(const bf16x8*)&sA[(wm + (mh * 2 + i) * 16 + l16) * 64 + sl];
                bfr[i][ks] = *(const bf16x8*)&sB[(wn + (nh * 2 + i) * 16 + l16) * 64 + sl];
            }
        }
        __builtin_amdgcn_s_setprio(1);
#pragma unroll
        for (int ks = 0; ks < 2; ++ks)
#pragma unroll
            for (int i = 0; i < 2; ++i)
#pragma unroll
                for (int j = 0; j < 2; ++j)
                    acc[mh * 2 + i][nh * 2 + j] = __builtin_amdgcn_mfma_f32_16x16x32_bf16(
                        af[i][ks], bfr[j][ks], acc[mh * 2 + i][nh * 2 + j], 0, 0, 0);
        __builtin_amdgcn_s_setprio(0);
    };

    // Per-tile window. rA/rB: buffer holding tile t (read). wA/wB: dead buffer
    // (tile t-1 fully read before B1) receiving tile t+1.
    auto tile_step = [&](const unsigned short* rA, const unsigned short* rB,
                         unsigned short* wA, unsigned short* wB, int kk, bool last) {
        BAR;                              // B1: all waves done reading wA/wB
        if (!last) { stA(wA, 0, kk); stB(wB, 0, kk); WAIT_VM2; }
        else       { WAIT_VM0; }
        BAR;                              // B2: tile t landed everywhere
        if (!last) { stA(wA, 1, kk); stB(wB, 1, kk); stA(wA, 2, kk); stA(wA, 3, kk); }
        do_quad(rA, rB, 0, 0);
        do_quad(rA, rB, 0, 1);
        do_quad(rA, rB, 1, 0);
        do_quad(rA, rB, 1, 1);
    };

    const int nt = K >> 6;                // 12 or 16: even, >= 4
    // prologue: tile 0 -> buf0 (6 loads: 4 A + 2 B)
    stA(As0, 0, 0); stB(Bs0, 0, 0); stA(As0, 1, 0); stB(Bs0, 1, 0);
    stA(As0, 2, 0); stA(As0, 3, 0);
    int kk = 64;
    for (int t = 0; t < nt - 2; t += 2) {
        tile_step(As0, Bs0, As1, Bs1, kk, false); kk += 64;   // tile t,   stage t+1
        tile_step(As1, Bs1, As0, Bs0, kk, false); kk += 64;   // tile t+1, stage t+2
    }
    tile_step(As0, Bs0, As1, Bs1, kk, false);                 // tile nt-2, stage nt-1
    tile_step(As1, Bs1, As0, Bs0, 0, true);                   // tile nt-1 (drain)

    // epilogue: C/D layout col=lane&15, row=quad*4+reg  [m89/m91 verified]
#pragma unroll
    for (int i = 0; i < 4; ++i) {
#pragma unroll
        for (int j = 0; j < 4; ++j) {
            const long r0 = row0 + wm + i * 16 + quad * 4;
            const long c  = col0 + wn + j * 16 + l16;
            const float bb = bias ? bias[c] : 0.0f;
#pragma unroll
            for (int r = 0; r < 4; ++r) {
                const float v = acc[i][j][r] * scale + bb;
                const long rr = r0 + r;
                if (Cb) {
                    if (transC) {
                        Cb[((rr >> 10) * 768 + c) * 1024 + (rr & 1023)] = f2bf(v);
                    } else {
                        Cb[rr * ldc + c] = f2bf(v);
                    }
                } else {
                    Cf[rr * ldc + c] = v;
                }
            }
        }
    }
}

// ---------------------------------------------------------------------------

__global__ __launch_bounds__(512, 2) void proj_qkv(
    const unsigned short* __restrict__ xb, const unsigned short* __restrict__ eb,
    const unsigned short* __restrict__ wqt, const unsigned short* __restrict__ wkt,
    const unsigned short* __restrict__ wvt,
    const float* __restrict__ bq, const float* __restrict__ bk,
    const float* __restrict__ bv,
    unsigned short* __restrict__ q, unsigned short* __restrict__ k,
    unsigned short* __restrict__ vt)
{
    const unsigned short *A, *Bt; const float* bias; unsigned short* C;
    int trans = 0;
    switch (blockIdx.z) {
        case 0:  A = xb; Bt = wqt; bias = bq; C = q;  break;
        case 1:  A = eb; Bt = wkt; bias = bk; C = k;  break;
        default: A = eb; Bt = wvt; bias = bv; C = vt; trans = 1; break;
    }
    const long row0 = (long)blockIdx.x * 256;
    const long col0 = (long)blockIdx.y * 128;
    gemm_core(A + row0 * 768, Bt + col0 * 768, 768,
              nullptr, C, 768, trans, bias, 1.0f, row0, col0);
}

__global__ __launch_bounds__(512, 2) void scores_gemm(
    const unsigned short* __restrict__ q, const unsigned short* __restrict__ k,
    float* __restrict__ sc, float scale)
{
    const long b    = blockIdx.z;
    const long row0 = (long)blockIdx.x * 256;    // within batch
    const long col0 = (long)blockIdx.y * 128;
    gemm_core(q + (b * 1024 + row0) * 768, k + b * 786432 + col0 * 768, 768,
              sc + b * 1048576, nullptr, 1024, 0, nullptr, scale, row0, col0);
}

__global__ __launch_bounds__(512, 2) void pv_gemm(
    const unsigned short* __restrict__ p, const unsigned short* __restrict__ vt,
    unsigned short* __restrict__ ao)
{
    const long b    = blockIdx.z;
    const long row0 = (long)blockIdx.x * 256;    // within batch
    const long col0 = (long)blockIdx.y * 128;
    gemm_core(p + (b * 1024 + row0) * 1024, vt + b * 786432 + col0 * 1024, 1024,
              nullptr, ao + b * 786432, 768, 0, nullptr, 1.0f, row0, col0);
}

__global__ __launch_bounds__(512, 2) void outproj_gemm(
    const unsigned short* __restrict__ ao, const unsigned short* __restrict__ wpt,
    float* __restrict__ out, const float* __restrict__ bp)
{
    const long row0 = (long)blockIdx.x * 256;
    const long col0 = (long)blockIdx.y * 128;
    gemm_core(ao + row0 * 768, wpt + col0 * 768, 768,
              out, nullptr, 768, 0, bp, 1.0f, row0, col0);
}

// ---------------------------------------------------------------------------

__global__ __launch_bounds__(256) void convert_inputs(
    const float* __restrict__ x, const float* __restrict__ enc,
    unsigned short* __restrict__ xb, unsigned short* __restrict__ eb, int nper)
{
    const int i = blockIdx.x * 256 + threadIdx.x;   // float4 index
    const bool second = (i >= nper);
    const int idx = second ? i - nper : i;
    const float4 v = second ? ((const float4*)enc)[idx] : ((const float4*)x)[idx];
    ushort4 o;
    o.x = f2bf(v.x); o.y = f2bf(v.y); o.z = f2bf(v.z); o.w = f2bf(v.w);
    if (second) ((ushort4*)eb)[idx] = o;
    else        ((ushort4*)xb)[idx] = o;
}

__global__ __launch_bounds__(256) void transpose_w(
    const float* __restrict__ w0, const float* __restrict__ w1,
    const float* __restrict__ w2, const float* __restrict__ w3,
    unsigned short* __restrict__ o0, unsigned short* __restrict__ o1,
    unsigned short* __restrict__ o2, unsigned short* __restrict__ o3)
{
    const float* w; unsigned short* o;
    switch (blockIdx.z) {
        case 0:  w = w0; o = o0; break;
        case 1:  w = w1; o = o1; break;
        case 2:  w = w2; o = o2; break;
        default: w = w3; o = o3; break;
    }
    __shared__ float t[32][33];
    const int tx = threadIdx.x & 31;
    const int ty = threadIdx.x >> 5;          // 0..7
    const int k0 = blockIdx.x * 32;
    const int n0 = blockIdx.y * 32;
#pragma unroll
    for (int i = 0; i < 4; ++i)
        t[ty + i * 8][tx] = w[(long)(k0 + ty + i * 8) * 768 + n0 + tx];
    __syncthreads();
#pragma unroll
    for (int i = 0; i < 4; ++i)
        o[(long)(n0 + ty + i * 8) * 768 + k0 + tx] = f2bf(t[tx][ty + i * 8]);
}

__global__ __launch_bounds__(256) void softmax_rows(
    const float* __restrict__ S, unsigned short* __restrict__ P)
{
    const long row = blockIdx.x;                 // 8192 rows of 1024
    const float* s = S + row * 1024;
    unsigned short* p = P + row * 1024;
    const int tid  = threadIdx.x;
    const int lane = tid & 63;
    const int wave = tid >> 6;

    float4 v = ((const float4*)s)[tid];
    float m = fmaxf(fmaxf(v.x, v.y), fmaxf(v.z, v.w));
#pragma unroll
    for (int off = 32; off > 0; off >>= 1)
        m = fmaxf(m, __shfl_xor(m, off));
    __shared__ float redm[4], reds[4];
    if (lane == 0) redm[wave] = m;
    __syncthreads();
    m = fmaxf(fmaxf(redm[0], redm[1]), fmaxf(redm[2], redm[3]));

    const float e0 = __expf(v.x - m), e1 = __expf(v.y - m);
    const float e2 = __expf(v.z - m), e3 = __expf(v.w - m);
    float sum = e0 + e1 + e2 + e3;
#pragma unroll
    for (int off = 32; off > 0; off >>= 1)
        sum += __shfl_xor(sum, off);
    if (lane == 0) reds[wave] = sum;
    __syncthreads();
    const float inv = 1.0f / (reds[0] + reds[1] + reds[2] + reds[3]);

    ushort4 o;
    o.x = f2bf(e0 * inv); o.y = f2bf(e1 * inv);
    o.z = f2bf(e2 * inv); o.w = f2bf(e3 * inv);
    ((ushort4*)p)[tid] = o;
}

// ---------------------------------------------------------------------------

extern "C" void kernel_launch(void* const* d_in, const int* in_sizes, int n_in,
                              void* d_out, int out_size, void* d_ws, size_t ws_size,
                              hipStream_t stream) {
    const float* x   = (const float*)d_in[0];
    const float* enc = (const float*)d_in[1];
    const float* Wq  = (const float*)d_in[2];
    const float* bq  = (const float*)d_in[3];
    const float* Wk  = (const float*)d_in[4];
    const float* bk  = (const float*)d_in[5];
    const float* Wv  = (const float*)d_in[6];
    const float* bv  = (const float*)d_in[7];
    const float* Wp  = (const float*)d_in[8];
    const float* bp  = (const float*)d_in[9];
    float* out = (float*)d_out;

    // workspace layout (bytes); peak need ~101.2 MB
    char* ws = (char*)d_ws;
    unsigned short* xb  = (unsigned short*)(ws + 0);         // 12582912
    unsigned short* eb  = (unsigned short*)(ws + 12582912);  // 12582912
    unsigned short* q   = (unsigned short*)(ws + 25165824);  // 12582912
    unsigned short* k   = (unsigned short*)(ws + 37748736);  // 12582912
    unsigned short* vt  = (unsigned short*)(ws + 50331648);  // 12582912 [B][H][S]
    unsigned short* wqt = (unsigned short*)(ws + 62914560);  // 1179648
    unsigned short* wkt = (unsigned short*)(ws + 64094208);  // 1179648
    unsigned short* wvt = (unsigned short*)(ws + 65273856);  // 1179648
    unsigned short* wpt = (unsigned short*)(ws + 66453504);  // 1179648
    float*          sc  = (float*)(ws + 67633152);           // 33554432 fp32 scores
    unsigned short* p   = (unsigned short*)(ws + 0);         // 16777216, overlays xb/eb (dead)
    unsigned short* ao  = (unsigned short*)(ws + 67633152);  // 12582912, overlays sc (dead)

    const float scale = 0.03608439182435161f;  // 1/sqrt(768)

    // 1. fp32 -> bf16 for x and encoder_out
    convert_inputs<<<12288, 256, 0, stream>>>(x, enc, xb, eb, 1572864);

    // 2. W^T bf16 for all four weights
    transpose_w<<<dim3(24, 24, 4), 256, 0, stream>>>(Wq, Wk, Wv, Wp, wqt, wkt, wvt, wpt);

    // 3. q/k/v projections: 256x128 tiles
    proj_qkv<<<dim3(32, 6, 3), 512, 0, stream>>>(xb, eb, wqt, wkt, wvt, bq, bk, bv, q, k, vt);

    // 4. scores = q k^T * scale (fp32)
    scores_gemm<<<dim3(4, 8, 8), 512, 0, stream>>>(q, k, sc, scale);

    // 5. softmax rows -> bf16 P
    softmax_rows<<<8192, 256, 0, stream>>>(sc, p);

    // 6. ao = P @ V
    pv_gemm<<<dim3(4, 6, 8), 512, 0, stream>>>(p, vt, ao);

    // 7. out = ao @ Wp + bp
    outproj_gemm<<<dim3(32, 6, 1), 512, 0, stream>>>(ao, wpt, out, bp);
}

// Round 3
// 247.345 us; speedup vs baseline: 1.0234x; 1.0234x over previous
//
#include <hip/hip_runtime.h>

// ---------------------------------------------------------------------------
// CrossAttention: B=8, T=S=1024, E=H=768, fp32 in/out, bf16 MFMA internally.
//
// Round 12: TRIPLE-buffered BK=32 pipeline (r10 kernel + depth-3 prefetch).
// Diagnosis chain: r10 doubled occupancy at zero speedup (stall is
// in-pipeline); r11 showed fewer-blocks/bigger-tile is worse. The real cost:
// 2-deep dbuf issues tile t+1's loads only ONE compute phase (~300 cy) before
// their vmcnt deadline vs ~900 cy HBM latency => ~600 cy stall per wait.
// Depth 3 gives each load ~3 compute phases of flight time.
//   prologue: stage tiles 0,1,2 (12 loads/wave in flight)
//   loop:     WAIT vmcnt(8) [tile t landed; t+1,t+2 in flight] ; BAR
//             compute(tile t) ; BAR ; stage(tile t+3 into t's buffer)
//   drain:    vmcnt(4), vmcnt(0) for last two tiles.
// LDS = 6 x 8 KiB = 48 KiB -> 3 blocks/CU (launch_bounds(256,3)).
// Swizzle/stage/compute byte-identical to r10 (harness-verified, 0 bank
// conflicts): phys slot s=(k+(r>>1))&3, read sl=((quad+(l16>>1))&3)*8,
// DMA src k=((lane&3)-(lane>>3))&3 per-lane, linear LDS dest.
// ---------------------------------------------------------------------------

typedef __bf16 bf16x8 __attribute__((ext_vector_type(8)));
typedef float  f32x4  __attribute__((ext_vector_type(4)));

#define WAIT_VM8 __builtin_amdgcn_s_waitcnt(0x0F78)   // vmcnt(8), lgkm/exp nowait
#define WAIT_VM4 __builtin_amdgcn_s_waitcnt(0x0F74)   // vmcnt(4)
#define WAIT_VM0 __builtin_amdgcn_s_waitcnt(0x0F70)   // vmcnt(0)
#define BAR      __builtin_amdgcn_s_barrier()

__device__ __forceinline__ unsigned short f2bf(float f) {
    unsigned int u = __float_as_uint(f);
    u += 0x7fffu + ((u >> 16) & 1u);   // RNE; inputs are finite
    return (unsigned short)(u >> 16);
}

__device__ __forceinline__ void async_copy16(const void* g, void* s) {
    __builtin_amdgcn_global_load_lds(
        (const __attribute__((address_space(1))) void*)g,
        (__attribute__((address_space(3))) void*)s, 16, 0, 0);
}

// Block computes C[row0:row0+128, col0:col0+128].
// Ag = A + row0*K ([*,K] bf16 row-major); Bg = B^T + col0*K ([*,K]).
// Exactly one of Cf/Cb non-null. transC: store C^T as [b][H][S] (vt).
__device__ __forceinline__ void gemm_core(
    const unsigned short* __restrict__ Ag,
    const unsigned short* __restrict__ Bg,
    const int K,
    float* __restrict__ Cf, unsigned short* __restrict__ Cb,
    const long ldc, const int transC, const float* __restrict__ bias,
    const float scale, const long row0, const long col0)
{
    __shared__ __align__(16) unsigned short As0[4096];   // [128][32] swizzled
    __shared__ __align__(16) unsigned short As1[4096];
    __shared__ __align__(16) unsigned short As2[4096];
    __shared__ __align__(16) unsigned short Bs0[4096];
    __shared__ __align__(16) unsigned short Bs1[4096];
    __shared__ __align__(16) unsigned short Bs2[4096];

    const int tid  = threadIdx.x;
    const int lane = tid & 63;
    const int quad = lane >> 4;
    const int l16  = lane & 15;
    const int wv   = tid >> 6;
    const int wm   = (wv >> 1) * 64;
    const int wn   = (wv & 1) * 64;

    // DMA staging: inst h, thread tid covers chunk c = h*256 + tid.
    // Dest row r = c>>2 (4 x 16B slots per 64B row), phys slot s = lane&3.
    // Stored k-chunk at (r,s) is k = (s - (r>>1)) & 3; since (wv*8, h*32)
    // vanish mod 4: k = ((lane&3) - (lane>>3)) & 3.
    const int j8 = ((((lane & 3) - (lane >> 3)) & 3)) * 8;  // src k-offset, elems
    const int rb = wv * 16 + (lane >> 2);                   // row for h=0
    const unsigned short* sa_src = Ag + (long)rb * K + j8;
    const unsigned short* sb_src = Bg + (long)rb * K + j8;
    const int dbase = (wv * 64 + lane) * 8;                 // LDS dst elems, h=0

    f32x4 acc[4][4];
#pragma unroll
    for (int i = 0; i < 4; ++i)
#pragma unroll
        for (int j = 0; j < 4; ++j)
            acc[i][j] = f32x4{0.f, 0.f, 0.f, 0.f};

    // one tile = 4 DMA instructions per thread (2 A + 2 B)
    auto stage = [&](unsigned short* dA, unsigned short* dB, int k0) {
#pragma unroll
        for (int h = 0; h < 2; ++h) {
            async_copy16(sa_src + (long)(h * 64) * K + k0, &dA[dbase + h * 2048]);
            async_copy16(sb_src + (long)(h * 64) * K + k0, &dB[dbase + h * 2048]);
        }
    };

    // 16 MFMA per wave per tile (single k-slab of 32)
    auto compute = [&](const unsigned short* sA, const unsigned short* sB) {
        bf16x8 af[4], bf[4];
        const int sl = ((quad + (l16 >> 1)) & 3) * 8;   // phys slot, elems
#pragma unroll
        for (int i = 0; i < 4; ++i) {
            af[i] = *(const bf16x8*)&sA[(wm + i * 16 + l16) * 32 + sl];
            bf[i] = *(const bf16x8*)&sB[(wn + i * 16 + l16) * 32 + sl];
        }
#pragma unroll
        for (int i = 0; i < 4; ++i)
#pragma unroll
            for (int j = 0; j < 4; ++j)
                acc[i][j] = __builtin_amdgcn_mfma_f32_16x16x32_bf16(
                    af[i], bf[j], acc[i][j], 0, 0, 0);
    };

    const int nk = K >> 5;            // 24 or 32 (>= 4)
    unsigned short *pA0 = As0, *pA1 = As1, *pA2 = As2;
    unsigned short *pB0 = Bs0, *pB1 = Bs1, *pB2 = Bs2;

    // prologue: 3 tiles in flight (12 loads/wave)
    stage(pA0, pB0, 0);
    stage(pA1, pB1, 32);
    stage(pA2, pB2, 64);
    int kk = 96;

    for (int t = 0; t < nk - 2; ++t) {
        WAIT_VM8; BAR;                // tile t landed everywhere (t+1,t+2 in flight)
        compute(pA0, pB0);
        BAR;                          // all waves done reading tile t's buffer
        if (t + 3 < nk) { stage(pA0, pB0, kk); kk += 32; }   // tile t+3
        unsigned short* tA = pA0; pA0 = pA1; pA1 = pA2; pA2 = tA;
        unsigned short* tB = pB0; pB0 = pB1; pB1 = pB2; pB2 = tB;
    }
    WAIT_VM4; BAR;                    // tile nk-2
    compute(pA0, pB0);
    WAIT_VM0; BAR;                    // tile nk-1
    compute(pA1, pB1);

    // epilogue: C/D layout col=lane&15, row=quad*4+reg  [m89/m91 verified]
#pragma unroll
    for (int i = 0; i < 4; ++i) {
#pragma unroll
        for (int j = 0; j < 4; ++j) {
            const long r0 = row0 + wm + i * 16 + quad * 4;
            const long c  = col0 + wn + j * 16 + l16;
            const float bb = bias ? bias[c] : 0.0f;
#pragma unroll
            for (int r = 0; r < 4; ++r) {
                const float v = acc[i][j][r] * scale + bb;
                const long rr = r0 + r;
                if (Cb) {
                    if (transC) {
                        Cb[((rr >> 10) * 768 + c) * 1024 + (rr & 1023)] = f2bf(v);
                    } else {
                        Cb[rr * ldc + c] = f2bf(v);
                    }
                } else {
                    Cf[rr * ldc + c] = v;
                }
            }
        }
    }
}

// ---------------------------------------------------------------------------

__global__ __launch_bounds__(256, 3) void proj_qkv(
    const unsigned short* __restrict__ xb, const unsigned short* __restrict__ eb,
    const unsigned short* __restrict__ wqt, const unsigned short* __restrict__ wkt,
    const unsigned short* __restrict__ wvt,
    const float* __restrict__ bq, const float* __restrict__ bk,
    const float* __restrict__ bv,
    unsigned short* __restrict__ q, unsigned short* __restrict__ k,
    unsigned short* __restrict__ vt)
{
    const unsigned short *A, *Bt; const float* bias; unsigned short* C;
    int trans = 0;
    switch (blockIdx.z) {
        case 0:  A = xb; Bt = wqt; bias = bq; C = q;  break;
        case 1:  A = eb; Bt = wkt; bias = bk; C = k;  break;
        default: A = eb; Bt = wvt; bias = bv; C = vt; trans = 1; break;
    }
    const long row0 = (long)blockIdx.x * 128;
    const long col0 = (long)blockIdx.y * 128;
    gemm_core(A + row0 * 768, Bt + col0 * 768, 768,
              nullptr, C, 768, trans, bias, 1.0f, row0, col0);
}

__global__ __launch_bounds__(256, 3) void scores_gemm(
    const unsigned short* __restrict__ q, const unsigned short* __restrict__ k,
    float* __restrict__ sc, float scale)
{
    const long b    = blockIdx.z;
    const long row0 = (long)blockIdx.x * 128;    // within batch
    const long col0 = (long)blockIdx.y * 128;
    gemm_core(q + (b * 1024 + row0) * 768, k + b * 786432 + col0 * 768, 768,
              sc + b * 1048576, nullptr, 1024, 0, nullptr, scale, row0, col0);
}

__global__ __launch_bounds__(256, 3) void pv_gemm(
    const unsigned short* __restrict__ p, const unsigned short* __restrict__ vt,
    unsigned short* __restrict__ ao)
{
    const long b    = blockIdx.z;
    const long row0 = (long)blockIdx.x * 128;    // within batch
    const long col0 = (long)blockIdx.y * 128;
    gemm_core(p + (b * 1024 + row0) * 1024, vt + b * 786432 + col0 * 1024, 1024,
              nullptr, ao + b * 786432, 768, 0, nullptr, 1.0f, row0, col0);
}

__global__ __launch_bounds__(256, 3) void outproj_gemm(
    const unsigned short* __restrict__ ao, const unsigned short* __restrict__ wpt,
    float* __restrict__ out, const float* __restrict__ bp)
{
    const long row0 = (long)blockIdx.x * 128;
    const long col0 = (long)blockIdx.y * 128;
    gemm_core(ao + row0 * 768, wpt + col0 * 768, 768,
              out, nullptr, 768, 0, bp, 1.0f, row0, col0);
}

// ---------------------------------------------------------------------------

__global__ __launch_bounds__(256) void convert_inputs(
    const float* __restrict__ x, const float* __restrict__ enc,
    unsigned short* __restrict__ xb, unsigned short* __restrict__ eb, int nper)
{
    const int i = blockIdx.x * 256 + threadIdx.x;   // float4 index
    const bool second = (i >= nper);
    const int idx = second ? i - nper : i;
    const float4 v = second ? ((const float4*)enc)[idx] : ((const float4*)x)[idx];
    ushort4 o;
    o.x = f2bf(v.x); o.y = f2bf(v.y); o.z = f2bf(v.z); o.w = f2bf(v.w);
    if (second) ((ushort4*)eb)[idx] = o;
    else        ((ushort4*)xb)[idx] = o;
}

__global__ __launch_bounds__(256) void transpose_w(
    const float* __restrict__ w0, const float* __restrict__ w1,
    const float* __restrict__ w2, const float* __restrict__ w3,
    unsigned short* __restrict__ o0, unsigned short* __restrict__ o1,
    unsigned short* __restrict__ o2, unsigned short* __restrict__ o3)
{
    const float* w; unsigned short* o;
    switch (blockIdx.z) {
        case 0:  w = w0; o = o0; break;
        case 1:  w = w1; o = o1; break;
        case 2:  w = w2; o = o2; break;
        default: w = w3; o = o3; break;
    }
    __shared__ float t[32][33];
    const int tx = threadIdx.x & 31;
    const int ty = threadIdx.x >> 5;          // 0..7
    const int k0 = blockIdx.x * 32;
    const int n0 = blockIdx.y * 32;
#pragma unroll
    for (int i = 0; i < 4; ++i)
        t[ty + i * 8][tx] = w[(long)(k0 + ty + i * 8) * 768 + n0 + tx];
    __syncthreads();
#pragma unroll
    for (int i = 0; i < 4; ++i)
        o[(long)(n0 + ty + i * 8) * 768 + k0 + tx] = f2bf(t[tx][ty + i * 8]);
}

__global__ __launch_bounds__(256) void softmax_rows(
    const float* __restrict__ S, unsigned short* __restrict__ P)
{
    const long row = blockIdx.x;                 // 8192 rows of 1024
    const float* s = S + row * 1024;
    unsigned short* p = P + row * 1024;
    const int tid  = threadIdx.x;
    const int lane = tid & 63;
    const int wave = tid >> 6;

    float4 v = ((const float4*)s)[tid];
    float m = fmaxf(fmaxf(v.x, v.y), fmaxf(v.z, v.w));
#pragma unroll
    for (int off = 32; off > 0; off >>= 1)
        m = fmaxf(m, __shfl_xor(m, off));
    __shared__ float redm[4], reds[4];
    if (lane == 0) redm[wave] = m;
    __syncthreads();
    m = fmaxf(fmaxf(redm[0], redm[1]), fmaxf(redm[2], redm[3]));

    const float e0 = __expf(v.x - m), e1 = __expf(v.y - m);
    const float e2 = __expf(v.z - m), e3 = __expf(v.w - m);
    float sum = e0 + e1 + e2 + e3;
#pragma unroll
    for (int off = 32; off > 0; off >>= 1)
        sum += __shfl_xor(sum, off);
    if (lane == 0) reds[wave] = sum;
    __syncthreads();
    const float inv = 1.0f / (reds[0] + reds[1] + reds[2] + reds[3]);

    ushort4 o;
    o.x = f2bf(e0 * inv); o.y = f2bf(e1 * inv);
    o.z = f2bf(e2 * inv); o.w = f2bf(e3 * inv);
    ((ushort4*)p)[tid] = o;
}

// ---------------------------------------------------------------------------

extern "C" void kernel_launch(void* const* d_in, const int* in_sizes, int n_in,
                              void* d_out, int out_size, void* d_ws, size_t ws_size,
                              hipStream_t stream) {
    const float* x   = (const float*)d_in[0];
    const float* enc = (const float*)d_in[1];
    const float* Wq  = (const float*)d_in[2];
    const float* bq  = (const float*)d_in[3];
    const float* Wk  = (const float*)d_in[4];
    const float* bk  = (const float*)d_in[5];
    const float* Wv  = (const float*)d_in[6];
    const float* bv  = (const float*)d_in[7];
    const float* Wp  = (const float*)d_in[8];
    const float* bp  = (const float*)d_in[9];
    float* out = (float*)d_out;

    // workspace layout (bytes); peak need ~101.2 MB
    char* ws = (char*)d_ws;
    unsigned short* xb  = (unsigned short*)(ws + 0);         // 12582912
    unsigned short* eb  = (unsigned short*)(ws + 12582912);  // 12582912
    unsigned short* q   = (unsigned short*)(ws + 25165824);  // 12582912
    unsigned short* k   = (unsigned short*)(ws + 37748736);  // 12582912
    unsigned short* vt  = (unsigned short*)(ws + 50331648);  // 12582912 [B][H][S]
    unsigned short* wqt = (unsigned short*)(ws + 62914560);  // 1179648
    unsigned short* wkt = (unsigned short*)(ws + 64094208);  // 1179648
    unsigned short* wvt = (unsigned short*)(ws + 65273856);  // 1179648
    unsigned short* wpt = (unsigned short*)(ws + 66453504);  // 1179648
    float*          sc  = (float*)(ws + 67633152);           // 33554432 fp32 scores
    unsigned short* p   = (unsigned short*)(ws + 0);         // 16777216, overlays xb/eb (dead)
    unsigned short* ao  = (unsigned short*)(ws + 67633152);  // 12582912, overlays sc (dead)

    const float scale = 0.03608439182435161f;  // 1/sqrt(768)

    // 1. fp32 -> bf16 for x and encoder_out
    convert_inputs<<<12288, 256, 0, stream>>>(x, enc, xb, eb, 1572864);

    // 2. W^T bf16 for all four weights
    transpose_w<<<dim3(24, 24, 4), 256, 0, stream>>>(Wq, Wk, Wv, Wp, wqt, wkt, wvt, wpt);

    // 3. q/k/v projections: 128x128 tiles
    proj_qkv<<<dim3(64, 6, 3), 256, 0, stream>>>(xb, eb, wqt, wkt, wvt, bq, bk, bv, q, k, vt);

    // 4. scores = q k^T * scale (fp32)
    scores_gemm<<<dim3(8, 8, 8), 256, 0, stream>>>(q, k, sc, scale);

    // 5. softmax rows -> bf16 P
    softmax_rows<<<8192, 256, 0, stream>>>(sc, p);

    // 6. ao = P @ V
    pv_gemm<<<dim3(8, 6, 8), 256, 0, stream>>>(p, vt, ao);

    // 7. out = ao @ Wp + bp
    outproj_gemm<<<dim3(64, 6, 1), 256, 0, stream>>>(ao, wpt, out, bp);
}

// Round 4
// 226.559 us; speedup vs baseline: 1.1173x; 1.0917x over previous
//
#include <hip/hip_runtime.h>

// ---------------------------------------------------------------------------
// CrossAttention: B=8, T=S=1024, E=H=768, fp32 in/out, bf16 MFMA internally.
//
// Round 13: r9 gemm_core VERBATIM (best measured: 57.5us proj, 238us total)
// + XCD-locality block mapping ONLY.
// Diagnosis: r10 (4blk/CU), r12 (depth-3) both null; r11 (1blk/CU) worse.
// Invariant across all: per-CU LDS-ingest rate ~12 B/cy. Candidate limit:
// operand re-reads (A-strips x6, B-tiles x64, ~442MB/GEMM) are served by L3
// (~10TB/s => ~44us floor) because consecutive blocks share NOTHING (row-major
// dispatch: reuse partners 64 ids apart, different XCDs). Fix: flat grid +
// XCD-chunked supertiles: physical p -> xcd g=p&7 (HW round-robin), member
// m=p>>3; group g covers rows g*8..g*8+7 x all cols => working set
// (8 A-strips 1.6MB + B 1.2MB) fits one XCD's 4MB L2, reuse partners
// temporally adjacent on the same XCD. scores/pv: one batch per XCD (~3.1MB).
// ---------------------------------------------------------------------------

typedef __bf16 bf16x8 __attribute__((ext_vector_type(8)));
typedef float  f32x4  __attribute__((ext_vector_type(4)));

#define WAIT_VM8 __builtin_amdgcn_s_waitcnt(0x0F78)   // vmcnt(8), lgkm/exp nowait
#define WAIT_VM0 __builtin_amdgcn_s_waitcnt(0x0F70)   // vmcnt(0)
#define BAR      __builtin_amdgcn_s_barrier()

__device__ __forceinline__ unsigned short f2bf(float f) {
    unsigned int u = __float_as_uint(f);
    u += 0x7fffu + ((u >> 16) & 1u);   // RNE; inputs are finite
    return (unsigned short)(u >> 16);
}

__device__ __forceinline__ void async_copy16(const void* g, void* s) {
    __builtin_amdgcn_global_load_lds(
        (const __attribute__((address_space(1))) void*)g,
        (__attribute__((address_space(3))) void*)s, 16, 0, 0);
}

// Block computes C[row0:row0+128, col0:col0+128].
// Ag = A + row0*K ([*,K] bf16 row-major); Bg = B^T + col0*K ([*,K]).
// Exactly one of Cf/Cb non-null. transC: store C^T as [b][H][S] (vt).
__device__ __forceinline__ void gemm_core(
    const unsigned short* __restrict__ Ag,
    const unsigned short* __restrict__ Bg,
    const int K,
    float* __restrict__ Cf, unsigned short* __restrict__ Cb,
    const long ldc, const int transC, const float* __restrict__ bias,
    const float scale, const long row0, const long col0)
{
    __shared__ __align__(16) unsigned short As0[8192];   // [128][64] swizzled
    __shared__ __align__(16) unsigned short As1[8192];
    __shared__ __align__(16) unsigned short Bs0[8192];
    __shared__ __align__(16) unsigned short Bs1[8192];

    const int tid  = threadIdx.x;
    const int lane = tid & 63;
    const int quad = lane >> 4;
    const int l16  = lane & 15;
    const int wv   = tid >> 6;
    const int wm   = (wv >> 1) * 64;
    const int wn   = (wv & 1) * 64;

    // DMA staging: chunk c = wv*256 + h*64 + lane covers row r=c>>3, linear
    // slot s=lane&7; source k-chunk j = s ^ (r&7) = (lane&7)^((lane>>3)&7).
    const int j8 = ((lane & 7) ^ ((lane >> 3) & 7)) * 8;   // src k-offset, elems
    const int rb = wv * 32 + (lane >> 3);                  // row for h=0
    const unsigned short* sa_src = Ag + (long)rb * K + j8;
    const unsigned short* sb_src = Bg + (long)rb * K + j8;
    const int dbase = (wv * 256 + lane) * 8;               // LDS dst elems, h=0

    f32x4 acc[4][4];
#pragma unroll
    for (int i = 0; i < 4; ++i)
#pragma unroll
        for (int j = 0; j < 4; ++j)
            acc[i][j] = f32x4{0.f, 0.f, 0.f, 0.f};

    // one tile = 8 DMA instructions per thread (4 A + 4 B)
    auto stage = [&](unsigned short* dA, unsigned short* dB, int k0) {
#pragma unroll
        for (int h = 0; h < 4; ++h) {
            async_copy16(sa_src + (long)(h * 8) * K + k0, &dA[dbase + h * 512]);
            async_copy16(sb_src + (long)(h * 8) * K + k0, &dB[dbase + h * 512]);
        }
    };

    // 32 MFMA per wave per tile (two k-halves of 32)
    auto compute = [&](const unsigned short* sA, const unsigned short* sB) {
#pragma unroll
        for (int h = 0; h < 2; ++h) {
            bf16x8 af[4], bf[4];
            const int sl = ((quad + h * 4) ^ (l16 & 7)) * 8;
#pragma unroll
            for (int i = 0; i < 4; ++i) {
                af[i] = *(const bf16x8*)&sA[(wm + i * 16 + l16) * 64 + sl];
                bf[i] = *(const bf16x8*)&sB[(wn + i * 16 + l16) * 64 + sl];
            }
#pragma unroll
            for (int i = 0; i < 4; ++i)
#pragma unroll
                for (int j = 0; j < 4; ++j)
                    acc[i][j] = __builtin_amdgcn_mfma_f32_16x16x32_bf16(
                        af[i], bf[j], acc[i][j], 0, 0, 0);
        }
    };

    const int nk = K >> 6;            // 12 or 16: even, >= 4
    stage(As0, Bs0, 0);               // tile 0 -> buf0   (8 loads)
    stage(As1, Bs1, 64);              // tile 1 -> buf1   (8 loads)
    int k0 = 128;

    for (int t = 0; t < nk - 2; t += 2) {
        WAIT_VM8; BAR;                // buf0 (tile t) landed everywhere
        compute(As0, Bs0);
        BAR;                          // all waves done reading buf0
        stage(As0, Bs0, k0); k0 += 64;        // tile t+2 -> buf0

        WAIT_VM8; BAR;                // buf1 (tile t+1) landed
        compute(As1, Bs1);
        BAR;
        stage(As1, Bs1, k0); k0 += 64;        // tile t+3 -> buf1
    }
    WAIT_VM8; BAR;                    // tile nk-2
    compute(As0, Bs0);
    WAIT_VM0; BAR;                    // tile nk-1
    compute(As1, Bs1);

    // epilogue: C/D layout col=lane&15, row=quad*4+reg  [m89/m91 verified]
#pragma unroll
    for (int i = 0; i < 4; ++i) {
#pragma unroll
        for (int j = 0; j < 4; ++j) {
            const long r0 = row0 + wm + i * 16 + quad * 4;
            const long c  = col0 + wn + j * 16 + l16;
            const float bb = bias ? bias[c] : 0.0f;
#pragma unroll
            for (int r = 0; r < 4; ++r) {
                const float v = acc[i][j][r] * scale + bb;
                const long rr = r0 + r;
                if (Cb) {
                    if (transC) {
                        Cb[((rr >> 10) * 768 + c) * 1024 + (rr & 1023)] = f2bf(v);
                    } else {
                        Cb[rr * ldc + c] = f2bf(v);
                    }
                } else {
                    Cf[rr * ldc + c] = v;
                }
            }
        }
    }
}

// ---------------------------------------------------------------------------
// XCD-locality mapping helpers (HW round-robins consecutive blockIdx.x over
// the 8 XCDs; grid sizes are multiples of 8 so the mapping is bijective).
//   p -> xcd g = p&7, member m = p>>3.

__global__ __launch_bounds__(256, 2) void proj_qkv(
    const unsigned short* __restrict__ xb, const unsigned short* __restrict__ eb,
    const unsigned short* __restrict__ wqt, const unsigned short* __restrict__ wkt,
    const unsigned short* __restrict__ wvt,
    const float* __restrict__ bq, const float* __restrict__ bk,
    const float* __restrict__ bv,
    unsigned short* __restrict__ q, unsigned short* __restrict__ k,
    unsigned short* __restrict__ vt)
{
    const unsigned short *A, *Bt; const float* bias; unsigned short* C;
    int trans = 0;
    switch (blockIdx.z) {
        case 0:  A = xb; Bt = wqt; bias = bq; C = q;  break;
        case 1:  A = eb; Bt = wkt; bias = bk; C = k;  break;
        default: A = eb; Bt = wvt; bias = bv; C = vt; trans = 1; break;
    }
    // p in [0,384): xcd g owns rows g*8..g*8+7 x all 6 cols (A 1.6MB + B 1.2MB
    // fits the XCD L2); within the group cols vary fastest after rows.
    const int p = blockIdx.x;
    const int g = p & 7, m = p >> 3;          // m in [0,48)
    const long row0 = (long)(g * 8 + (m & 7)) * 128;
    const long col0 = (long)(m >> 3) * 128;
    gemm_core(A + row0 * 768, Bt + col0 * 768, 768,
              nullptr, C, 768, trans, bias, 1.0f, row0, col0);
}

__global__ __launch_bounds__(256, 2) void scores_gemm(
    const unsigned short* __restrict__ q, const unsigned short* __restrict__ k,
    float* __restrict__ sc, float scale)
{
    // p in [0,512): batch b = p&7 pinned to one XCD (Q+K strips ~3.1MB in L2).
    const int p = blockIdx.x;
    const long b = p & 7;
    const int m  = p >> 3;                    // [0,64)
    const long row0 = (long)(m & 7) * 128;
    const long col0 = (long)(m >> 3) * 128;
    gemm_core(q + (b * 1024 + row0) * 768, k + b * 786432 + col0 * 768, 768,
              sc + b * 1048576, nullptr, 1024, 0, nullptr, scale, row0, col0);
}

__global__ __launch_bounds__(256, 2) void pv_gemm(
    const unsigned short* __restrict__ p_, const unsigned short* __restrict__ vt,
    unsigned short* __restrict__ ao)
{
    // p in [0,384): batch b = p&7 pinned to one XCD (P strips 2MB + Vt 1.5MB).
    const int p = blockIdx.x;
    const long b = p & 7;
    const int m  = p >> 3;                    // [0,48)
    const long row0 = (long)(m & 7) * 128;
    const long col0 = (long)(m >> 3) * 128;
    gemm_core(p_ + (b * 1024 + row0) * 1024, vt + b * 786432 + col0 * 1024, 1024,
              nullptr, ao + b * 786432, 768, 0, nullptr, 1.0f, row0, col0);
}

__global__ __launch_bounds__(256, 2) void outproj_gemm(
    const unsigned short* __restrict__ ao, const unsigned short* __restrict__ wpt,
    float* __restrict__ out, const float* __restrict__ bp)
{
    const int p = blockIdx.x;                 // [0,384)
    const int g = p & 7, m = p >> 3;
    const long row0 = (long)(g * 8 + (m & 7)) * 128;
    const long col0 = (long)(m >> 3) * 128;
    gemm_core(ao + row0 * 768, wpt + col0 * 768, 768,
              out, nullptr, 768, 0, bp, 1.0f, row0, col0);
}

// ---------------------------------------------------------------------------

__global__ __launch_bounds__(256) void convert_inputs(
    const float* __restrict__ x, const float* __restrict__ enc,
    unsigned short* __restrict__ xb, unsigned short* __restrict__ eb, int nper)
{
    const int i = blockIdx.x * 256 + threadIdx.x;   // float4 index
    const bool second = (i >= nper);
    const int idx = second ? i - nper : i;
    const float4 v = second ? ((const float4*)enc)[idx] : ((const float4*)x)[idx];
    ushort4 o;
    o.x = f2bf(v.x); o.y = f2bf(v.y); o.z = f2bf(v.z); o.w = f2bf(v.w);
    if (second) ((ushort4*)eb)[idx] = o;
    else        ((ushort4*)xb)[idx] = o;
}

__global__ __launch_bounds__(256) void transpose_w(
    const float* __restrict__ w0, const float* __restrict__ w1,
    const float* __restrict__ w2, const float* __restrict__ w3,
    unsigned short* __restrict__ o0, unsigned short* __restrict__ o1,
    unsigned short* __restrict__ o2, unsigned short* __restrict__ o3)
{
    const float* w; unsigned short* o;
    switch (blockIdx.z) {
        case 0:  w = w0; o = o0; break;
        case 1:  w = w1; o = o1; break;
        case 2:  w = w2; o = o2; break;
        default: w = w3; o = o3; break;
    }
    __shared__ float t[32][33];
    const int tx = threadIdx.x & 31;
    const int ty = threadIdx.x >> 5;          // 0..7
    const int k0 = blockIdx.x * 32;
    const int n0 = blockIdx.y * 32;
#pragma unroll
    for (int i = 0; i < 4; ++i)
        t[ty + i * 8][tx] = w[(long)(k0 + ty + i * 8) * 768 + n0 + tx];
    __syncthreads();
#pragma unroll
    for (int i = 0; i < 4; ++i)
        o[(long)(n0 + ty + i * 8) * 768 + k0 + tx] = f2bf(t[tx][ty + i * 8]);
}

__global__ __launch_bounds__(256) void softmax_rows(
    const float* __restrict__ S, unsigned short* __restrict__ P)
{
    const long row = blockIdx.x;                 // 8192 rows of 1024
    const float* s = S + row * 1024;
    unsigned short* p = P + row * 1024;
    const int tid  = threadIdx.x;
    const int lane = tid & 63;
    const int wave = tid >> 6;

    float4 v = ((const float4*)s)[tid];
    float m = fmaxf(fmaxf(v.x, v.y), fmaxf(v.z, v.w));
#pragma unroll
    for (int off = 32; off > 0; off >>= 1)
        m = fmaxf(m, __shfl_xor(m, off));
    __shared__ float redm[4], reds[4];
    if (lane == 0) redm[wave] = m;
    __syncthreads();
    m = fmaxf(fmaxf(redm[0], redm[1]), fmaxf(redm[2], redm[3]));

    const float e0 = __expf(v.x - m), e1 = __expf(v.y - m);
    const float e2 = __expf(v.z - m), e3 = __expf(v.w - m);
    float sum = e0 + e1 + e2 + e3;
#pragma unroll
    for (int off = 32; off > 0; off >>= 1)
        sum += __shfl_xor(sum, off);
    if (lane == 0) reds[wave] = sum;
    __syncthreads();
    const float inv = 1.0f / (reds[0] + reds[1] + reds[2] + reds[3]);

    ushort4 o;
    o.x = f2bf(e0 * inv); o.y = f2bf(e1 * inv);
    o.z = f2bf(e2 * inv); o.w = f2bf(e3 * inv);
    ((ushort4*)p)[tid] = o;
}

// ---------------------------------------------------------------------------

extern "C" void kernel_launch(void* const* d_in, const int* in_sizes, int n_in,
                              void* d_out, int out_size, void* d_ws, size_t ws_size,
                              hipStream_t stream) {
    const float* x   = (const float*)d_in[0];
    const float* enc = (const float*)d_in[1];
    const float* Wq  = (const float*)d_in[2];
    const float* bq  = (const float*)d_in[3];
    const float* Wk  = (const float*)d_in[4];
    const float* bk  = (const float*)d_in[5];
    const float* Wv  = (const float*)d_in[6];
    const float* bv  = (const float*)d_in[7];
    const float* Wp  = (const float*)d_in[8];
    const float* bp  = (const float*)d_in[9];
    float* out = (float*)d_out;

    // workspace layout (bytes); peak need ~101.2 MB
    char* ws = (char*)d_ws;
    unsigned short* xb  = (unsigned short*)(ws + 0);         // 12582912
    unsigned short* eb  = (unsigned short*)(ws + 12582912);  // 12582912
    unsigned short* q   = (unsigned short*)(ws + 25165824);  // 12582912
    unsigned short* k   = (unsigned short*)(ws + 37748736);  // 12582912
    unsigned short* vt  = (unsigned short*)(ws + 50331648);  // 12582912 [B][H][S]
    unsigned short* wqt = (unsigned short*)(ws + 62914560);  // 1179648
    unsigned short* wkt = (unsigned short*)(ws + 64094208);  // 1179648
    unsigned short* wvt = (unsigned short*)(ws + 65273856);  // 1179648
    unsigned short* wpt = (unsigned short*)(ws + 66453504);  // 1179648
    float*          sc  = (float*)(ws + 67633152);           // 33554432 fp32 scores
    unsigned short* p   = (unsigned short*)(ws + 0);         // 16777216, overlays xb/eb (dead)
    unsigned short* ao  = (unsigned short*)(ws + 67633152);  // 12582912, overlays sc (dead)

    const float scale = 0.03608439182435161f;  // 1/sqrt(768)

    // 1. fp32 -> bf16 for x and encoder_out
    convert_inputs<<<12288, 256, 0, stream>>>(x, enc, xb, eb, 1572864);

    // 2. W^T bf16 for all four weights
    transpose_w<<<dim3(24, 24, 4), 256, 0, stream>>>(Wq, Wk, Wv, Wp, wqt, wkt, wvt, wpt);

    // 3. q/k/v projections: 128x128 tiles, XCD-grouped flat grid
    proj_qkv<<<dim3(384, 1, 3), 256, 0, stream>>>(xb, eb, wqt, wkt, wvt, bq, bk, bv, q, k, vt);

    // 4. scores = q k^T * scale (fp32), one batch per XCD
    scores_gemm<<<dim3(512, 1, 1), 256, 0, stream>>>(q, k, sc, scale);

    // 5. softmax rows -> bf16 P
    softmax_rows<<<8192, 256, 0, stream>>>(sc, p);

    // 6. ao = P @ V, one batch per XCD
    pv_gemm<<<dim3(384, 1, 1), 256, 0, stream>>>(p, vt, ao);

    // 7. out = ao @ Wp + bp
    outproj_gemm<<<dim3(384, 1, 1), 256, 0, stream>>>(ao, wpt, out, bp);
}